// Round 4
// baseline (434.321 us; speedup 1.0000x reference)
//
#include <hip/hip_runtime.h>
#include <hip/hip_bf16.h>
#include <cstdint>
#include <cstddef>

#define B_  64
#define S_  2048
#define E_  512
#define C_  512
#define H_  256

using f32x4 = __attribute__((ext_vector_type(4))) float;
using s16x8 = __attribute__((ext_vector_type(8))) short;

// packed fp32x4 -> bf16x4 (RNE)
__device__ __forceinline__ uint2 f4_to_bf4(float4 v) {
    __hip_bfloat162 lo = __float22bfloat162_rn(make_float2(v.x, v.y));
    __hip_bfloat162 hi = __float22bfloat162_rn(make_float2(v.z, v.w));
    union { __hip_bfloat162 b; unsigned u; } a, c;
    a.b = lo; c.b = hi;
    return make_uint2(a.u, c.u);
}

// async global->LDS DMA, 16 B per lane; lds dest = wave-uniform base + lane*16
__device__ __forceinline__ void async16(const void* g, void* l) {
    __builtin_amdgcn_global_load_lds(
        (const __attribute__((address_space(1))) void*)g,
        (__attribute__((address_space(3))) void*)l,
        16, 0, 0);
}

// ---- merged prep: blocks 0..127 convert W_word to bf16; blocks 128..191 do
// cb[b][h] = ctx[b]@W_ctx[h]^T + b_ctx[h] + b_word[h] ----
__global__ void prep_kernel(const float* __restrict__ W, unsigned short* __restrict__ Wb,
                            const float* __restrict__ ctx, const float* __restrict__ Wc,
                            const float* __restrict__ bc, const float* __restrict__ bw,
                            float* __restrict__ cb) {
    __shared__ float row[C_];
    int blk = blockIdx.x, t = threadIdx.x;
    if (blk < 128) {
        int i = (blk * 256 + t) * 4;
        float4 v = *(const float4*)(W + i);
        *(uint2*)(Wb + i) = f4_to_bf4(v);
    } else {
        int b = blk - 128;
        row[t] = ctx[b * C_ + t];
        row[t + 256] = ctx[b * C_ + t + 256];
        __syncthreads();
        const float4* w4 = (const float4*)(Wc + (size_t)t * C_);
        const float4* x4 = (const float4*)row;
        float acc = 0.f;
        #pragma unroll 4
        for (int c = 0; c < C_ / 4; ++c) {
            float4 w = w4[c], x = x4[c];
            acc += w.x * x.x + w.y * x.y + w.z * x.z + w.w * x.w;
        }
        cb[b * H_ + t] = acc + bc[t] + bw[t];
    }
}

// ---- main: scores + fused flash-style slab partials ----
// GEMM now DOUBLE-BUFFERED, single barrier per K-step (T3 minimum-2-phase):
//   issue B-DMA(t+1) + A-reg-loads(t+1) -> compute(t) -> cvt+ds_write A(t+1)
//   -> __syncthreads (drains DMA vmcnt + lgkm) -> swap.
// Staging latency (HBM ~900cy / L2 ~200cy) hides under compute (~700cy).
// LDS ~103 KB -> 1 block/CU (HK pattern: in-block prefetch self-hides).
// Swizzles / fragment math unchanged from the known-good 83 us kernel.
// Epilogue: wave-parallel slab softmax partials (was 128-serial per thread).
#define BM 128
#define BN 256
#define BK 64
#define LDT 72   // padded LDS row stride for A (shorts)

__global__ __launch_bounds__(512) void scores_kernel(
    const float* __restrict__ A,            // [B*S, E] fp32
    const unsigned short* __restrict__ Wb,  // [H, E] bf16
    const float* __restrict__ cb,           // [B, H]
    const float* __restrict__ wh,           // [H]
    const int*   __restrict__ lens,         // [B]
    float* __restrict__ scores,             // [B*S] raw scores
    float* __restrict__ Wpart,              // [B*S/BM, E] slab partial features
    float* __restrict__ mtpart)             // [B*S/BM, 2]  (m_l, t_l)
{
    __shared__ __align__(16) unsigned short At[2][BM * LDT];   // 2 x 18.4 KB
    __shared__ __align__(16) unsigned short Bt[2][BN * 64];    // 2 x 32 KB, DMA target
    __shared__ float sblk[BM];
    __shared__ float pblk[BM];
    __shared__ float wred[2], wredt[2];
    int t = threadIdx.x;
    int m0 = blockIdx.x * BM;
    int b  = m0 >> 11;   // /S_
    int ms = m0 & (S_ - 1);
    int len = lens[b];
    if (ms >= len) return;   // fully-masked slab: dead work (finalize skips it)

    int w = t >> 6, lane = t & 63, quad = lane >> 4, lm = lane & 15;
    int wm = (w & 1) * 64, wn = (w >> 1) * 64;

    if (t < BM) sblk[t] = 0.f;

    f32x4 acc[4][4] = {};

    int arow = t >> 4, acol = (t & 15) * 4;  // A staging: 32 rows/sweep, 4 sweeps
    int la8 = lane >> 3, lc8 = lane & 7;     // B DMA: 8 rows/inst, 8 chunks/row

    // ---- prologue: stage k0=0 into buffer 0 ----
    #pragma unroll
    for (int j = 0; j < 4; ++j) {
        int r  = (w << 5) + (j << 3) + la8;
        int cg = (lc8 ^ (r & 7)) << 3;               // swizzled global short offset
        async16(Wb + (size_t)r * E_ + cg,
                (char*)Bt[0] + (((w << 5) + (j << 3)) << 7));
    }
    {
        float4 av[4];
        #pragma unroll
        for (int i = 0; i < 4; ++i)
            av[i] = *(const float4*)(A + (size_t)(m0 + arow + i * 32) * E_ + acol);
        #pragma unroll
        for (int i = 0; i < 4; ++i)
            *(uint2*)(At[0] + (arow + i * 32) * LDT + acol) = f4_to_bf4(av[i]);
    }
    __syncthreads();

    int cur = 0;
    for (int step = 0; step < 8; ++step) {
        int nxt = cur ^ 1;
        int k1 = (step + 1) * BK;
        float4 av[4];
        if (step < 7) {
            // B(t+1): 8 waves x 4 DMA insts -> in flight across compute
            #pragma unroll
            for (int j = 0; j < 4; ++j) {
                int r  = (w << 5) + (j << 3) + la8;
                int cg = (lc8 ^ (r & 7)) << 3;
                async16(Wb + (size_t)r * E_ + k1 + cg,
                        (char*)Bt[nxt] + (((w << 5) + (j << 3)) << 7));
            }
            // A(t+1): global -> regs (HBM latency hides under compute)
            #pragma unroll
            for (int i = 0; i < 4; ++i)
                av[i] = *(const float4*)(A + (size_t)(m0 + arow + i * 32) * E_ + k1 + acol);
        }
        // compute step t from cur
        #pragma unroll
        for (int ks = 0; ks < 2; ++ks) {
            s16x8 af[4], bfr[4];
            #pragma unroll
            for (int i = 0; i < 4; ++i)
                af[i] = *(const s16x8*)(At[cur] + (wm + i * 16 + lm) * LDT + ks * 32 + quad * 8);
            #pragma unroll
            for (int i = 0; i < 4; ++i) {
                int r = wn + i * 16 + lm;
                int c = (ks * 4 + quad) ^ (r & 7);
                bfr[i] = *(const s16x8*)(Bt[cur] + r * 64 + c * 8);
            }
            #pragma unroll
            for (int mi = 0; mi < 4; ++mi)
                #pragma unroll
                for (int ni = 0; ni < 4; ++ni)
                    acc[mi][ni] = __builtin_amdgcn_mfma_f32_16x16x32_bf16(
                        af[mi], bfr[ni], acc[mi][ni], 0, 0, 0);
        }
        if (step < 7) {
            #pragma unroll
            for (int i = 0; i < 4; ++i)
                *(uint2*)(At[nxt] + (arow + i * 32) * LDT + acol) = f4_to_bf4(av[i]);
        }
        __syncthreads();   // drains B-DMA (vmcnt) + A ds_writes (lgkm) for nxt
        cur = nxt;
    }

    float wv[4], cbv[4];
    #pragma unroll
    for (int ni = 0; ni < 4; ++ni) {
        int n = wn + ni * 16 + lm;
        wv[ni]  = wh[n];
        cbv[ni] = cb[b * H_ + n];
    }
    #pragma unroll
    for (int mi = 0; mi < 4; ++mi) {
        #pragma unroll
        for (int r = 0; r < 4; ++r) {
            float p = 0.f;
            #pragma unroll
            for (int ni = 0; ni < 4; ++ni) {
                float x = acc[mi][ni][r] + cbv[ni];
                x = fminf(fmaxf(x, -15.f), 15.f);
                float e = __expf(2.f * x);
                float th = 1.f - 2.f * __builtin_amdgcn_rcpf(e + 1.f);
                p += wv[ni] * th;
            }
            #pragma unroll
            for (int off = 8; off >= 1; off >>= 1)
                p += __shfl_xor(p, off);
            if (lm == 0)
                atomicAdd(&sblk[wm + mi * 16 + quad * 4 + r], p);
        }
    }
    __syncthreads();
    if (t < BM) scores[m0 + t] = sblk[t];   // raw scores (finalize normalizes attn)

    // ---- fused epilogue: wave-parallel slab softmax partials ----
    int nvalid = len - ms; if (nvalid > BM) nvalid = BM;   // >= 1 here
    if (t < 128) {
        float v = (t < nvalid) ? sblk[t] : -1e30f;
        float mm = v;
        #pragma unroll
        for (int off = 32; off >= 1; off >>= 1) mm = fmaxf(mm, __shfl_xor(mm, off));
        if ((t & 63) == 0) wred[t >> 6] = mm;
    }
    __syncthreads();
    float m_l = fmaxf(wred[0], wred[1]);
    if (t < 128) {
        float p = (t < nvalid) ? __expf(sblk[t] - m_l) : 0.f;
        pblk[t] = p;
        #pragma unroll
        for (int off = 32; off >= 1; off >>= 1) p += __shfl_xor(p, off);
        if ((t & 63) == 0) wredt[t >> 6] = p;
    }
    __syncthreads();
    // W_l[t] = sum_r pblk[r] * A[m0+r][t]; coalesced 2 KB/row, slab is L2/L3-hot
    float accw = 0.f;
    const float* ab = A + (size_t)m0 * E_ + t;
    #pragma unroll 8
    for (int r = 0; r < BM; ++r)
        accw += pblk[r] * ab[(size_t)r * E_];   // pblk=0 pads masked rows
    Wpart[(size_t)blockIdx.x * E_ + t] = accw;
    if (t == 0) {
        mtpart[blockIdx.x * 2 + 0] = m_l;
        mtpart[blockIdx.x * 2 + 1] = wredt[0] + wredt[1];
    }
}

// ---- finalize: merge slab partials per batch; write feat + normalized attn ----
__global__ __launch_bounds__(512) void finalize_kernel(
    const int* __restrict__ lens, const float* __restrict__ Wpart,
    const float* __restrict__ mtpart,
    float* __restrict__ attn,    // holds raw scores on entry; rewritten
    float* __restrict__ feat)
{
    int b = blockIdx.x, t = threadIdx.x;
    int len = lens[b];
    int L = (len + BM - 1) / BM;       // active slabs, 1..16
    int base = b * (S_ / BM);
    float M = -1e30f;
    for (int l = 0; l < L; ++l) M = fmaxf(M, mtpart[(base + l) * 2]);
    float T = 0.f;
    for (int l = 0; l < L; ++l)
        T += __expf(mtpart[(base + l) * 2] - M) * mtpart[(base + l) * 2 + 1];
    float inv = 1.f / T;
    // feat[b][t] = sum_l e^{m_l-M} * W_l[t] / T
    float acc = 0.f;
    for (int l = 0; l < L; ++l)
        acc += __expf(mtpart[(base + l) * 2] - M) * Wpart[(size_t)(base + l) * E_ + t];
    feat[b * E_ + t] = acc * inv;
    // attn[b][s] = e^{v-M}/T for s<len else 0
    float* sc = attn + (size_t)b * S_;
    #pragma unroll
    for (int i = 0; i < 4; ++i) {
        int s = t + i * 512;
        float v = sc[s];
        sc[s] = (s < len) ? __expf(v - M) * inv : 0.f;
    }
}

extern "C" void kernel_launch(void* const* d_in, const int* in_sizes, int n_in,
                              void* d_out, int out_size, void* d_ws, size_t ws_size,
                              hipStream_t stream) {
    const float* embeds = (const float*)d_in[0];
    const int*   lens   = (const int*)d_in[1];
    const float* ctx    = (const float*)d_in[2];
    const float* Ww     = (const float*)d_in[3];
    const float* bw     = (const float*)d_in[4];
    const float* Wc     = (const float*)d_in[5];
    const float* bc     = (const float*)d_in[6];
    const float* wh     = (const float*)d_in[7];
    float* out  = (float*)d_out;
    float* feat = out;                 // [B, E]
    float* attn = out + B_ * E_;       // [B, S] raw scores, then attn; 0 for s>=len

    char* ws = (char*)d_ws;
    unsigned short* Wb = (unsigned short*)ws;                         // 256 KB
    float* cb     = (float*)(ws + 256 * 1024);                        // 64 KB
    float* Wpart  = (float*)(ws + 320 * 1024);                        // 1024*512*4 = 2 MB
    float* mtpart = (float*)(ws + 320 * 1024 + 2 * 1024 * 1024);      // 8 KB

    prep_kernel<<<192, 256, 0, stream>>>(Ww, Wb, ctx, Wc, bc, bw, cb);
    scores_kernel<<<dim3(B_ * S_ / BM), 512, 0, stream>>>(embeds, Wb, cb, wh, lens,
                                                          attn, Wpart, mtpart);
    finalize_kernel<<<B_, 512, 0, stream>>>(lens, Wpart, mtpart, attn, feat);
}

// Round 5
// 424.490 us; speedup vs baseline: 1.0232x; 1.0232x over previous
//
#include <hip/hip_runtime.h>
#include <hip/hip_bf16.h>
#include <cstdint>
#include <cstddef>

#define B_  64
#define S_  2048
#define E_  512
#define C_  512
#define H_  256

using f32x4 = __attribute__((ext_vector_type(4))) float;
using s16x8 = __attribute__((ext_vector_type(8))) short;

// packed fp32x4 -> bf16x4 (RNE)
__device__ __forceinline__ uint2 f4_to_bf4(float4 v) {
    __hip_bfloat162 lo = __float22bfloat162_rn(make_float2(v.x, v.y));
    __hip_bfloat162 hi = __float22bfloat162_rn(make_float2(v.z, v.w));
    union { __hip_bfloat162 b; unsigned u; } a, c;
    a.b = lo; c.b = hi;
    return make_uint2(a.u, c.u);
}

// async global->LDS DMA, 16 B per lane; lds dest = wave-uniform base + lane*16
__device__ __forceinline__ void async16(const void* g, void* l) {
    __builtin_amdgcn_global_load_lds(
        (const __attribute__((address_space(1))) void*)g,
        (__attribute__((address_space(3))) void*)l,
        16, 0, 0);
}

// ---- merged prep: blocks 0..127 convert W_word to bf16; blocks 128..191 do
// cb[b][h] = ctx[b]@W_ctx[h]^T + b_ctx[h] + b_word[h] ----
__global__ void prep_kernel(const float* __restrict__ W, unsigned short* __restrict__ Wb,
                            const float* __restrict__ ctx, const float* __restrict__ Wc,
                            const float* __restrict__ bc, const float* __restrict__ bw,
                            float* __restrict__ cb) {
    __shared__ float row[C_];
    int blk = blockIdx.x, t = threadIdx.x;
    if (blk < 128) {
        int i = (blk * 256 + t) * 4;
        float4 v = *(const float4*)(W + i);
        *(uint2*)(Wb + i) = f4_to_bf4(v);
    } else {
        int b = blk - 128;
        row[t] = ctx[b * C_ + t];
        row[t + 256] = ctx[b * C_ + t + 256];
        __syncthreads();
        const float4* w4 = (const float4*)(Wc + (size_t)t * C_);
        const float4* x4 = (const float4*)row;
        float acc = 0.f;
        #pragma unroll 4
        for (int c = 0; c < C_ / 4; ++c) {
            float4 w = w4[c], x = x4[c];
            acc += w.x * x.x + w.y * x.y + w.z * x.z + w.w * x.w;
        }
        cb[b * H_ + t] = acc + bc[t] + bw[t];
    }
}

// ---- main: scores + fused flash-style slab partials ----
// A-ONLY double-buffer (R4 post-mortem: full dbuf -> 103 KB LDS -> 1 block/CU
// -> +25 us; m132 occupancy cliff). Bt stays single (B is L2-resident, ~200cy
// restage fits between barriers). LDS ~71 KB -> 2 blocks/CU preserved.
// Per step: issue A(t+1) HBM loads BEFORE compute(t)  [HBM latency hides
// under MFMA]; barrier; issue B(t+1) DMA + cvt/ds_write A(t+1); barrier.
// Same 2 barriers/step as the known-good 83us loop, but A is pipelined 1 deep.
#define BM 128
#define BN 256
#define BK 64
#define LDT 72   // padded LDS row stride for A (shorts)

__global__ __launch_bounds__(512, 4) void scores_kernel(
    const float* __restrict__ A,            // [B*S, E] fp32
    const unsigned short* __restrict__ Wb,  // [H, E] bf16
    const float* __restrict__ cb,           // [B, H]
    const float* __restrict__ wh,           // [H]
    const int*   __restrict__ lens,         // [B]
    float* __restrict__ scores,             // [B*S] raw scores
    float* __restrict__ Wpart,              // [B*S/BM, E] slab partial features
    float* __restrict__ mtpart)             // [B*S/BM, 2]  (m_l, t_l)
{
    __shared__ __align__(16) unsigned short At[2][BM * LDT];   // 2 x 18.4 KB
    __shared__ __align__(16) unsigned short Bt[BN * 64];       // 32 KB, DMA target
    __shared__ float sblk[BM];
    __shared__ float pblk[BM];
    __shared__ float wred[2], wredt[2];
    int t = threadIdx.x;
    int m0 = blockIdx.x * BM;
    int b  = m0 >> 11;   // /S_
    int ms = m0 & (S_ - 1);
    int len = lens[b];
    if (ms >= len) return;   // fully-masked slab: dead work (finalize skips it)

    int w = t >> 6, lane = t & 63, quad = lane >> 4, lm = lane & 15;
    int wm = (w & 1) * 64, wn = (w >> 1) * 64;

    if (t < BM) sblk[t] = 0.f;

    f32x4 acc[4][4] = {};

    int arow = t >> 4, acol = (t & 15) * 4;  // A staging: 32 rows/sweep, 4 sweeps
    int la8 = lane >> 3, lc8 = lane & 7;     // B DMA: 8 rows/inst, 8 chunks/row
    int bds = (w << 5);                      // wave's B LDS row base

    // ---- prologue: stage k=0 (B via DMA, A via reg+cvt) ----
    #pragma unroll
    for (int j = 0; j < 4; ++j) {
        int r  = bds + (j << 3) + la8;
        int cg = (lc8 ^ (r & 7)) << 3;               // swizzled global short offset
        async16(Wb + (size_t)r * E_ + cg,
                (char*)Bt + ((bds + (j << 3)) << 7));
    }
    {
        float4 av[4];
        #pragma unroll
        for (int i = 0; i < 4; ++i)
            av[i] = *(const float4*)(A + (size_t)(m0 + arow + i * 32) * E_ + acol);
        #pragma unroll
        for (int i = 0; i < 4; ++i)
            *(uint2*)(At[0] + (arow + i * 32) * LDT + acol) = f4_to_bf4(av[i]);
    }
    __syncthreads();   // drains B DMA (vmcnt) + A ds_writes (lgkm)

    int cur = 0;
    for (int step = 0; step < 8; ++step) {
        int k1 = (step + 1) * BK;
        float4 av[4];
        if (step < 7) {
            // A(t+1): issue HBM loads now; they land during compute(t)
            #pragma unroll
            for (int i = 0; i < 4; ++i)
                av[i] = *(const float4*)(A + (size_t)(m0 + arow + i * 32) * E_ + k1 + acol);
        }
        // compute step t from At[cur], Bt
        #pragma unroll
        for (int ks = 0; ks < 2; ++ks) {
            s16x8 af[4], bfr[4];
            #pragma unroll
            for (int i = 0; i < 4; ++i)
                af[i] = *(const s16x8*)(At[cur] + (wm + i * 16 + lm) * LDT + ks * 32 + quad * 8);
            #pragma unroll
            for (int i = 0; i < 4; ++i) {
                int r = wn + i * 16 + lm;
                int c = (ks * 4 + quad) ^ (r & 7);
                bfr[i] = *(const s16x8*)(Bt + r * 64 + c * 8);
            }
            #pragma unroll
            for (int mi = 0; mi < 4; ++mi)
                #pragma unroll
                for (int ni = 0; ni < 4; ++ni)
                    acc[mi][ni] = __builtin_amdgcn_mfma_f32_16x16x32_bf16(
                        af[mi], bfr[ni], acc[mi][ni], 0, 0, 0);
        }
        __syncthreads();   // all waves done reading Bt (and At[cur^1] from t-1)
        if (step < 7) {
            // B(t+1): L2-resident, short latency; drains at next barrier
            #pragma unroll
            for (int j = 0; j < 4; ++j) {
                int r  = bds + (j << 3) + la8;
                int cg = (lc8 ^ (r & 7)) << 3;
                async16(Wb + (size_t)r * E_ + k1 + cg,
                        (char*)Bt + ((bds + (j << 3)) << 7));
            }
            // A(t+1): cvt + ds_write into the other buffer
            #pragma unroll
            for (int i = 0; i < 4; ++i)
                *(uint2*)(At[cur ^ 1] + (arow + i * 32) * LDT + acol) = f4_to_bf4(av[i]);
        }
        __syncthreads();   // drains B DMA (vmcnt) + A ds_writes (lgkm)
        cur ^= 1;
    }

    float wv[4], cbv[4];
    #pragma unroll
    for (int ni = 0; ni < 4; ++ni) {
        int n = wn + ni * 16 + lm;
        wv[ni]  = wh[n];
        cbv[ni] = cb[b * H_ + n];
    }
    #pragma unroll
    for (int mi = 0; mi < 4; ++mi) {
        #pragma unroll
        for (int r = 0; r < 4; ++r) {
            float p = 0.f;
            #pragma unroll
            for (int ni = 0; ni < 4; ++ni) {
                float x = acc[mi][ni][r] + cbv[ni];
                x = fminf(fmaxf(x, -15.f), 15.f);
                float e = __expf(2.f * x);
                float th = 1.f - 2.f * __builtin_amdgcn_rcpf(e + 1.f);
                p += wv[ni] * th;
            }
            #pragma unroll
            for (int off = 8; off >= 1; off >>= 1)
                p += __shfl_xor(p, off);
            if (lm == 0)
                atomicAdd(&sblk[wm + mi * 16 + quad * 4 + r], p);
        }
    }
    __syncthreads();
    if (t < BM) scores[m0 + t] = sblk[t];   // raw scores (finalize normalizes attn)

    // ---- fused epilogue: wave-parallel slab softmax partials ----
    int nvalid = len - ms; if (nvalid > BM) nvalid = BM;   // >= 1 here
    if (t < 128) {
        float v = (t < nvalid) ? sblk[t] : -1e30f;
        float mm = v;
        #pragma unroll
        for (int off = 32; off >= 1; off >>= 1) mm = fmaxf(mm, __shfl_xor(mm, off));
        if ((t & 63) == 0) wred[t >> 6] = mm;
    }
    __syncthreads();
    float m_l = fmaxf(wred[0], wred[1]);
    if (t < 128) {
        float p = (t < nvalid) ? __expf(sblk[t] - m_l) : 0.f;
        pblk[t] = p;
        #pragma unroll
        for (int off = 32; off >= 1; off >>= 1) p += __shfl_xor(p, off);
        if ((t & 63) == 0) wredt[t >> 6] = p;
    }
    __syncthreads();
    // W_l[t] = sum_r pblk[r] * A[m0+r][t]; coalesced 2 KB/row, slab is L2/L3-hot
    float accw = 0.f;
    const float* ab = A + (size_t)m0 * E_ + t;
    #pragma unroll 8
    for (int r = 0; r < BM; ++r)
        accw += pblk[r] * ab[(size_t)r * E_];   // pblk=0 pads masked rows
    Wpart[(size_t)blockIdx.x * E_ + t] = accw;
    if (t == 0) {
        mtpart[blockIdx.x * 2 + 0] = m_l;
        mtpart[blockIdx.x * 2 + 1] = wredt[0] + wredt[1];
    }
}

// ---- finalize: merge slab partials per batch; write feat + normalized attn ----
__global__ __launch_bounds__(512) void finalize_kernel(
    const int* __restrict__ lens, const float* __restrict__ Wpart,
    const float* __restrict__ mtpart,
    float* __restrict__ attn,    // holds raw scores on entry; rewritten
    float* __restrict__ feat)
{
    int b = blockIdx.x, t = threadIdx.x;
    int len = lens[b];
    int L = (len + BM - 1) / BM;       // active slabs, 1..16
    int base = b * (S_ / BM);
    float M = -1e30f;
    for (int l = 0; l < L; ++l) M = fmaxf(M, mtpart[(base + l) * 2]);
    float T = 0.f;
    for (int l = 0; l < L; ++l)
        T += __expf(mtpart[(base + l) * 2] - M) * mtpart[(base + l) * 2 + 1];
    float inv = 1.f / T;
    // feat[b][t] = sum_l e^{m_l-M} * W_l[t] / T
    float acc = 0.f;
    for (int l = 0; l < L; ++l)
        acc += __expf(mtpart[(base + l) * 2] - M) * Wpart[(size_t)(base + l) * E_ + t];
    feat[b * E_ + t] = acc * inv;
    // attn[b][s] = e^{v-M}/T for s<len else 0
    float* sc = attn + (size_t)b * S_;
    #pragma unroll
    for (int i = 0; i < 4; ++i) {
        int s = t + i * 512;
        float v = sc[s];
        sc[s] = (s < len) ? __expf(v - M) * inv : 0.f;
    }
}

extern "C" void kernel_launch(void* const* d_in, const int* in_sizes, int n_in,
                              void* d_out, int out_size, void* d_ws, size_t ws_size,
                              hipStream_t stream) {
    const float* embeds = (const float*)d_in[0];
    const int*   lens   = (const int*)d_in[1];
    const float* ctx    = (const float*)d_in[2];
    const float* Ww     = (const float*)d_in[3];
    const float* bw     = (const float*)d_in[4];
    const float* Wc     = (const float*)d_in[5];
    const float* bc     = (const float*)d_in[6];
    const float* wh     = (const float*)d_in[7];
    float* out  = (float*)d_out;
    float* feat = out;                 // [B, E]
    float* attn = out + B_ * E_;       // [B, S] raw scores, then attn; 0 for s>=len

    char* ws = (char*)d_ws;
    unsigned short* Wb = (unsigned short*)ws;                         // 256 KB
    float* cb     = (float*)(ws + 256 * 1024);                        // 64 KB
    float* Wpart  = (float*)(ws + 320 * 1024);                        // 1024*512*4 = 2 MB
    float* mtpart = (float*)(ws + 320 * 1024 + 2 * 1024 * 1024);      // 8 KB

    prep_kernel<<<192, 256, 0, stream>>>(Ww, Wb, ctx, Wc, bc, bw, cb);
    scores_kernel<<<dim3(B_ * S_ / BM), 512, 0, stream>>>(embeds, Wb, cb, wh, lens,
                                                          attn, Wpart, mtpart);
    finalize_kernel<<<B_, 512, 0, stream>>>(lens, Wpart, mtpart, attn, feat);
}

// Round 6
// 423.242 us; speedup vs baseline: 1.0262x; 1.0029x over previous
//
#include <hip/hip_runtime.h>
#include <hip/hip_bf16.h>
#include <cstdint>
#include <cstddef>

#define B_  64
#define S_  2048
#define E_  512
#define C_  512
#define H_  256

using f32x4 = __attribute__((ext_vector_type(4))) float;
using s16x8 = __attribute__((ext_vector_type(8))) short;

// packed fp32x4 -> bf16x4 (RNE)
__device__ __forceinline__ uint2 f4_to_bf4(float4 v) {
    __hip_bfloat162 lo = __float22bfloat162_rn(make_float2(v.x, v.y));
    __hip_bfloat162 hi = __float22bfloat162_rn(make_float2(v.z, v.w));
    union { __hip_bfloat162 b; unsigned u; } a, c;
    a.b = lo; c.b = hi;
    return make_uint2(a.u, c.u);
}

// async global->LDS DMA, 16 B per lane; lds dest = wave-uniform base + lane*16
__device__ __forceinline__ void async16(const void* g, void* l) {
    __builtin_amdgcn_global_load_lds(
        (const __attribute__((address_space(1))) void*)g,
        (__attribute__((address_space(3))) void*)l,
        16, 0, 0);
}

// ---- merged prep: blocks 0..127 convert W_word to bf16; blocks 128..191 do
// cb[b][h] = ctx[b]@W_ctx[h]^T + b_ctx[h] + b_word[h] ----
__global__ void prep_kernel(const float* __restrict__ W, unsigned short* __restrict__ Wb,
                            const float* __restrict__ ctx, const float* __restrict__ Wc,
                            const float* __restrict__ bc, const float* __restrict__ bw,
                            float* __restrict__ cb) {
    __shared__ float row[C_];
    int blk = blockIdx.x, t = threadIdx.x;
    if (blk < 128) {
        int i = (blk * 256 + t) * 4;
        float4 v = *(const float4*)(W + i);
        *(uint2*)(Wb + i) = f4_to_bf4(v);
    } else {
        int b = blk - 128;
        row[t] = ctx[b * C_ + t];
        row[t + 256] = ctx[b * C_ + t + 256];
        __syncthreads();
        const float4* w4 = (const float4*)(Wc + (size_t)t * C_);
        const float4* x4 = (const float4*)row;
        float acc = 0.f;
        #pragma unroll 4
        for (int c = 0; c < C_ / 4; ++c) {
            float4 w = w4[c], x = x4[c];
            acc += w.x * x.x + w.y * x.y + w.z * x.z + w.w * x.w;
        }
        cb[b * H_ + t] = acc + bc[t] + bw[t];
    }
}

// ---- main: scores[b,s] = w_hidden . tanh(embeds[b,s]@W_word^T + cb[b]) ----
// R0 structure (stage -> barrier -> compute -> barrier; known-good 83 us),
// RETILED to BM=64 / 256 threads / 4-wave blocks:
//   LDS 42 KB (was 51) + VGPR<=128 (__launch_bounds__(256,4)) -> 3 blocks/CU
//   (was 2) in 3 INDEPENDENT 4-wave barrier domains (was 2x8-wave). During a
//   domain's vmcnt(0) barrier drain, 8 waves of 2 other domains keep issuing
//   HBM loads -> higher staging duty cycle on the BW-bound A stream.
//   Ragged mask tail also halves (avg 32 wasted rows/batch vs 64).
// Swizzles / fragment math / epilogue identical to the 83 us kernel.
#define BM 64
#define BN 256
#define BK 64
#define LDT 72   // padded LDS row stride for A (shorts)

__global__ __launch_bounds__(256, 4) void scores_kernel(
    const float* __restrict__ A,            // [B*S, E] fp32
    const unsigned short* __restrict__ Wb,  // [H, E] bf16
    const float* __restrict__ cb,           // [B, H]
    const float* __restrict__ wh,           // [H]
    const int*   __restrict__ lens,         // [B]
    float* __restrict__ scores)             // [B*S]
{
    __shared__ __align__(16) unsigned short At[BM * LDT];   // 9.2 KB, padded
    __shared__ __align__(16) unsigned short Bt[BN * 64];    // 32 KB, DMA target (no pad)
    __shared__ float sblk[BM];
    int t = threadIdx.x;
    int m0 = blockIdx.x * BM;
    int b  = m0 >> 11;   // /S_
    int ms = m0 & (S_ - 1);
    if (ms >= lens[b]) return;   // fully-masked slab: dead work

    int w = t >> 6, lane = t & 63, quad = lane >> 4, lm = lane & 15;
    int wn = w * 64;             // wave owns n = wn..wn+63, all m = 0..63

    if (t < BM) sblk[t] = 0.f;

    f32x4 acc[4][4] = {};

    int arow = t >> 4, acol = (t & 15) * 4;  // A staging: 16 rows/sweep, 4 sweeps
    int la8 = lane >> 3, lc8 = lane & 7;     // B DMA: 8 rows/inst, 8 chunks/row

    for (int k0 = 0; k0 < E_; k0 += BK) {
        // B: 4 waves x 8 DMA insts -> 256 rows x 128 B (issued first, stays in flight)
        #pragma unroll
        for (int j = 0; j < 8; ++j) {
            int r  = (w << 6) + (j << 3) + la8;
            int cg = (lc8 ^ (r & 7)) << 3;               // swizzled global short offset
            async16(Wb + (size_t)r * E_ + k0 + cg,
                    (char*)Bt + (((w << 6) + (j << 3)) << 7));
        }
        // A: register roundtrip, convert once at staging (64 rows x 64 cols fp32)
        #pragma unroll
        for (int i = 0; i < 4; ++i) {
            int r = arow + i * 16;
            float4 v = *(const float4*)(A + (size_t)(m0 + r) * E_ + k0 + acol);
            *(uint2*)(At + r * LDT + acol) = f4_to_bf4(v);
        }
        __syncthreads();
        #pragma unroll
        for (int ks = 0; ks < 2; ++ks) {
            s16x8 af[4], bfr[4];
            #pragma unroll
            for (int i = 0; i < 4; ++i)
                af[i] = *(const s16x8*)(At + (i * 16 + lm) * LDT + ks * 32 + quad * 8);
            #pragma unroll
            for (int i = 0; i < 4; ++i) {
                int r = wn + i * 16 + lm;
                int c = (ks * 4 + quad) ^ (r & 7);
                bfr[i] = *(const s16x8*)(Bt + r * 64 + c * 8);
            }
            #pragma unroll
            for (int mi = 0; mi < 4; ++mi)
                #pragma unroll
                for (int ni = 0; ni < 4; ++ni)
                    acc[mi][ni] = __builtin_amdgcn_mfma_f32_16x16x32_bf16(
                        af[mi], bfr[ni], acc[mi][ni], 0, 0, 0);
        }
        __syncthreads();
    }

    float wv[4], cbv[4];
    #pragma unroll
    for (int ni = 0; ni < 4; ++ni) {
        int n = wn + ni * 16 + lm;
        wv[ni]  = wh[n];
        cbv[ni] = cb[b * H_ + n];
    }
    #pragma unroll
    for (int mi = 0; mi < 4; ++mi) {
        #pragma unroll
        for (int r = 0; r < 4; ++r) {
            float p = 0.f;
            #pragma unroll
            for (int ni = 0; ni < 4; ++ni) {
                float x = acc[mi][ni][r] + cbv[ni];
                x = fminf(fmaxf(x, -15.f), 15.f);
                float e = __expf(2.f * x);
                float th = 1.f - 2.f * __builtin_amdgcn_rcpf(e + 1.f);
                p += wv[ni] * th;
            }
            #pragma unroll
            for (int off = 8; off >= 1; off >>= 1)
                p += __shfl_xor(p, off);
            if (lm == 0)
                atomicAdd(&sblk[mi * 16 + quad * 4 + r], p);
        }
    }
    __syncthreads();
    if (t < BM) scores[m0 + t] = sblk[t];
}

// ---- masked softmax over s<len; attn=0 for s>=len. Also zeroes feat[b,:]
// (wsum accumulates with atomics and runs after this in stream order).
__global__ void softmax_kernel(const int* __restrict__ lens, float* __restrict__ attn,
                               float* __restrict__ feat) {
    __shared__ float redm[4], redt[4];
    int b = blockIdx.x, t = threadIdx.x;
    int len = lens[b];
    float* sc = attn + (size_t)b * S_;
    feat[b * E_ + t] = 0.f;
    feat[b * E_ + 256 + t] = 0.f;
    float v[8];
    #pragma unroll
    for (int i = 0; i < 8; ++i) {
        int s = t + i * 256;
        v[i] = (s < len) ? sc[s] : -1e30f;
    }
    float m = -1e30f;
    #pragma unroll
    for (int i = 0; i < 8; ++i) m = fmaxf(m, v[i]);
    #pragma unroll
    for (int off = 32; off >= 1; off >>= 1) m = fmaxf(m, __shfl_xor(m, off));
    if ((t & 63) == 0) redm[t >> 6] = m;
    __syncthreads();
    m = fmaxf(fmaxf(redm[0], redm[1]), fmaxf(redm[2], redm[3]));
    float e[8]; float tm = 0.f;
    #pragma unroll
    for (int i = 0; i < 8; ++i) {
        int s = t + i * 256;
        e[i] = (s < len) ? __expf(v[i] - m) : 0.f;
        tm += e[i];
    }
    #pragma unroll
    for (int off = 32; off >= 1; off >>= 1) tm += __shfl_xor(tm, off);
    if ((t & 63) == 0) redt[t >> 6] = tm;
    __syncthreads();
    tm = redt[0] + redt[1] + redt[2] + redt[3];
    float sfac = 1.f / tm;
    #pragma unroll
    for (int i = 0; i < 8; ++i) {
        int s = t + i * 256;
        sc[s] = e[i] * sfac;
    }
}

// ---- attention_features[b,e] = sum_{s<len} attn[b,s]*embeds[b,s,e] ----
__global__ __launch_bounds__(512) void wsum_kernel(
    const float* __restrict__ A, const float* __restrict__ attn,
    const int* __restrict__ lens, float* __restrict__ out) {
    int b = blockIdx.y;
    int len = lens[b];
    int s0 = blockIdx.x * 128;
    if (s0 >= len) return;
    int send = s0 + 128; if (send > len) send = len;
    int t  = threadIdx.x;
    int e4 = t & 127;   // float4 column
    int sr = t >> 7;    // row group 0..3
    const float* ap = attn + (size_t)b * S_;
    f32x4 acc = {0.f, 0.f, 0.f, 0.f};
    const float* base = A + (size_t)b * S_ * E_;
    for (int s = s0 + sr; s < send; s += 4) {
        float wgt = ap[s];
        f32x4 v = *(const f32x4*)(base + (size_t)s * E_ + e4 * 4);
        acc += wgt * v;
    }
    __shared__ f32x4 red[4][128];
    red[sr][e4] = acc;
    __syncthreads();
    if (t < 128) {
        f32x4 tot = red[0][t] + red[1][t] + red[2][t] + red[3][t];
        float* o = out + (size_t)b * E_ + t * 4;
        atomicAdd(o + 0, tot[0]);
        atomicAdd(o + 1, tot[1]);
        atomicAdd(o + 2, tot[2]);
        atomicAdd(o + 3, tot[3]);
    }
}

extern "C" void kernel_launch(void* const* d_in, const int* in_sizes, int n_in,
                              void* d_out, int out_size, void* d_ws, size_t ws_size,
                              hipStream_t stream) {
    const float* embeds = (const float*)d_in[0];
    const int*   lens   = (const int*)d_in[1];
    const float* ctx    = (const float*)d_in[2];
    const float* Ww     = (const float*)d_in[3];
    const float* bw     = (const float*)d_in[4];
    const float* Wc     = (const float*)d_in[5];
    const float* bc     = (const float*)d_in[6];
    const float* wh     = (const float*)d_in[7];
    float* out  = (float*)d_out;
    float* feat = out;                 // [B, E]
    float* attn = out + B_ * E_;       // [B, S] (raw scores, then attn; 0 for s>=len)

    unsigned short* Wb = (unsigned short*)d_ws;                                  // 256 KB
    float* cb = (float*)((char*)d_ws + (size_t)H_ * E_ * sizeof(unsigned short)); // 64 KB

    prep_kernel<<<192, 256, 0, stream>>>(Ww, Wb, ctx, Wc, bc, bw, cb);
    scores_kernel<<<dim3(B_ * S_ / BM), 256, 0, stream>>>(embeds, Wb, cb, wh, lens, attn);
    softmax_kernel<<<B_, 256, 0, stream>>>(lens, attn, feat);
    wsum_kernel<<<dim3(S_ / 128, B_), 512, 0, stream>>>(embeds, attn, lens, feat);
}

// Round 7
// 410.898 us; speedup vs baseline: 1.0570x; 1.0300x over previous
//
#include <hip/hip_runtime.h>
#include <hip/hip_bf16.h>
#include <cstdint>
#include <cstddef>

#define B_  64
#define S_  2048
#define E_  512
#define C_  512
#define H_  256

using f32x4 = __attribute__((ext_vector_type(4))) float;
using s16x8 = __attribute__((ext_vector_type(8))) short;

// packed fp32x4 -> bf16x4 (RNE)
__device__ __forceinline__ uint2 f4_to_bf4(float4 v) {
    __hip_bfloat162 lo = __float22bfloat162_rn(make_float2(v.x, v.y));
    __hip_bfloat162 hi = __float22bfloat162_rn(make_float2(v.z, v.w));
    union { __hip_bfloat162 b; unsigned u; } a, c;
    a.b = lo; c.b = hi;
    return make_uint2(a.u, c.u);
}

// 8 consecutive fp32 -> bf16x8 fragment (RNE), in-register
__device__ __forceinline__ s16x8 pack_bf8(float4 a, float4 b) {
    union { s16x8 v; uint2 u[2]; } r;
    r.u[0] = f4_to_bf4(a);
    r.u[1] = f4_to_bf4(b);
    return r.v;
}

// async global->LDS DMA, 16 B per lane; lds dest = wave-uniform base + lane*16
__device__ __forceinline__ void async16(const void* g, void* l) {
    __builtin_amdgcn_global_load_lds(
        (const __attribute__((address_space(1))) void*)g,
        (__attribute__((address_space(3))) void*)l,
        16, 0, 0);
}

// ---- merged prep: blocks 0..127 convert W_word to bf16; blocks 128..191 do
// cb[b][h] = ctx[b]@W_ctx[h]^T + b_ctx[h] + b_word[h] ----
__global__ void prep_kernel(const float* __restrict__ W, unsigned short* __restrict__ Wb,
                            const float* __restrict__ ctx, const float* __restrict__ Wc,
                            const float* __restrict__ bc, const float* __restrict__ bw,
                            float* __restrict__ cb) {
    __shared__ float row[C_];
    int blk = blockIdx.x, t = threadIdx.x;
    if (blk < 128) {
        int i = (blk * 256 + t) * 4;
        float4 v = *(const float4*)(W + i);
        *(uint2*)(Wb + i) = f4_to_bf4(v);
    } else {
        int b = blk - 128;
        row[t] = ctx[b * C_ + t];
        row[t + 256] = ctx[b * C_ + t + 256];
        __syncthreads();
        const float4* w4 = (const float4*)(Wc + (size_t)t * C_);
        const float4* x4 = (const float4*)row;
        float acc = 0.f;
        #pragma unroll 4
        for (int c = 0; c < C_ / 4; ++c) {
            float4 w = w4[c], x = x4[c];
            acc += w.x * x.x + w.y * x.y + w.z * x.z + w.w * x.w;
        }
        cb[b * H_ + t] = acc + bc[t] + bw[t];
    }
}

// ---- main: scores[b,s] = w_hidden . tanh(embeds[b,s]@W_word^T + cb[b]) ----
// T3 "minimum 2-phase" schedule (§5.5): double-buffered At/Bt at BK=32
// (53 KB LDS -> occupancy unchanged at 2 blocks/CU), ONE raw s_barrier per
// K-step with counted waits via inline asm. Per step:
//   issue A(t+1) fp32 loads + B(t+1) DMA into buf^1   (latency -> under MFMA)
//   ds_read buf + 16 MFMA
//   cvt+ds_write A(t+1)        (compiler waits vmcnt(A) AFTER compute)
//   s_waitcnt vmcnt(0) lgkmcnt(0); s_barrier
// Fixes R5's failure mode: __syncthreads() drains vmcnt(0) unconditionally,
// swallowing any in-flight prefetch; raw barrier + own counted wait does not.
// MFMA k-order identical to the R0 83us kernel => scores bitwise identical.
#define BM 128
#define BN 256
#define BK 32
#define NT (E_ / BK)   // 16
#define LDT 40         // padded LDS row stride for A (shorts): 32 + 8

__global__ __launch_bounds__(512, 4) void scores_kernel(
    const float* __restrict__ A,            // [B*S, E] fp32
    const unsigned short* __restrict__ Wb,  // [H, E] bf16
    const float* __restrict__ cb,           // [B, H]
    const float* __restrict__ wh,           // [H]
    const int*   __restrict__ lens,         // [B]
    float* __restrict__ scores)             // [B*S]
{
    __shared__ __align__(16) unsigned short At[2][BM * LDT];  // 2 x 10 KB
    __shared__ __align__(16) unsigned short Bt[2][BN * BK];   // 2 x 16 KB, DMA target
    __shared__ float sblk[BM];
    int t = threadIdx.x;
    int m0 = blockIdx.x * BM;
    int b  = m0 >> 11;   // /S_
    int ms = m0 & (S_ - 1);
    if (ms >= lens[b]) return;   // fully-masked slab: dead work

    int w = t >> 6, lane = t & 63, quad = lane >> 4, lm = lane & 15;
    int wm = (w & 1) * 64, wn = (w >> 1) * 64;

    if (t < BM) sblk[t] = 0.f;

    f32x4 acc[4][4] = {};

    // A staging: thread t -> row t>>2, 8 floats at col (t&3)*8
    int arow = t >> 2, acol = (t & 3) * 8;
    const float* asrc = A + (size_t)(m0 + arow) * E_ + acol;
    unsigned short* adst0 = At[0] + arow * LDT + acol;
    unsigned short* adst1 = At[1] + arow * LDT + acol;

    // B DMA: wave w covers rows w*32 + j*16 + (lane>>2), chunk lane&3 (16 B)
    int rb = (w << 5) + (lane >> 2);
    int cb4 = lane & 3;
    const unsigned short* bs0 = Wb + (size_t)rb * E_ + ((cb4 ^ (rb & 3)) << 3);
    const unsigned short* bs1 = bs0 + (size_t)16 * E_;   // (rb+16)&3 == rb&3
    int bofs0 = w << 11;            // (w*32)*64 bytes
    int bofs1 = bofs0 + 1024;       // +16 rows

    // ---- prologue: stage k=0 into buffer 0 ----
    {
        async16(bs0, (char*)Bt[0] + bofs0);
        async16(bs1, (char*)Bt[0] + bofs1);
        float4 a0 = *(const float4*)(asrc);
        float4 a1 = *(const float4*)(asrc + 4);
        *(s16x8*)adst0 = pack_bf8(a0, a1);
    }
    __syncthreads();

    int cur = 0;
    for (int step = 0; step < NT; ++step) {
        bool pf = (step < NT - 1);
        int k1 = (step + 1) * BK;
        float4 av0, av1;
        if (pf) {
            // A(t+1): issue HBM loads first (oldest in vmcnt queue)
            av0 = *(const float4*)(asrc + k1);
            av1 = *(const float4*)(asrc + k1 + 4);
            // B(t+1): L2-resident DMA into the other buffer
            async16(bs0 + k1, (char*)Bt[cur ^ 1] + bofs0);
            async16(bs1 + k1, (char*)Bt[cur ^ 1] + bofs1);
        }
        // compute step t from buffer cur
        {
            const unsigned short* Atc = At[cur];
            const unsigned short* Btc = Bt[cur];
            s16x8 af[4], bfr[4];
            #pragma unroll
            for (int i = 0; i < 4; ++i)
                af[i] = *(const s16x8*)(Atc + (wm + i * 16 + lm) * LDT + quad * 8);
            #pragma unroll
            for (int i = 0; i < 4; ++i) {
                int r = wn + i * 16 + lm;
                bfr[i] = *(const s16x8*)(Btc + r * BK + ((quad ^ (r & 3)) << 3));
            }
            #pragma unroll
            for (int mi = 0; mi < 4; ++mi)
                #pragma unroll
                for (int ni = 0; ni < 4; ++ni)
                    acc[mi][ni] = __builtin_amdgcn_mfma_f32_16x16x32_bf16(
                        af[mi], bfr[ni], acc[mi][ni], 0, 0, 0);
        }
        if (pf) {
            // cvt waits only on av (B-DMA is younger in the queue); the A HBM
            // latency ran under the ds_reads + MFMA above
            *(s16x8*)(cur ? adst0 : adst1) = pack_bf8(av0, av1);
        }
        // own staging drained (B-DMA vmcnt + A ds_write lgkm), then rendezvous
        asm volatile("s_waitcnt vmcnt(0) lgkmcnt(0)" ::: "memory");
        __builtin_amdgcn_s_barrier();
        cur ^= 1;
    }

    float wv[4], cbv[4];
    #pragma unroll
    for (int ni = 0; ni < 4; ++ni) {
        int n = wn + ni * 16 + lm;
        wv[ni]  = wh[n];
        cbv[ni] = cb[b * H_ + n];
    }
    #pragma unroll
    for (int mi = 0; mi < 4; ++mi) {
        #pragma unroll
        for (int r = 0; r < 4; ++r) {
            float p = 0.f;
            #pragma unroll
            for (int ni = 0; ni < 4; ++ni) {
                float x = acc[mi][ni][r] + cbv[ni];
                x = fminf(fmaxf(x, -15.f), 15.f);
                float e = __expf(2.f * x);
                float th = 1.f - 2.f * __builtin_amdgcn_rcpf(e + 1.f);
                p += wv[ni] * th;
            }
            #pragma unroll
            for (int off = 8; off >= 1; off >>= 1)
                p += __shfl_xor(p, off);
            if (lm == 0)
                atomicAdd(&sblk[wm + mi * 16 + quad * 4 + r], p);
        }
    }
    __syncthreads();
    if (t < BM) scores[m0 + t] = sblk[t];
}

// ---- masked softmax over s<len; attn=0 for s>=len. Also zeroes feat[b,:]
// (wsum accumulates with atomics and runs after this in stream order).
__global__ void softmax_kernel(const int* __restrict__ lens, float* __restrict__ attn,
                               float* __restrict__ feat) {
    __shared__ float redm[4], redt[4];
    int b = blockIdx.x, t = threadIdx.x;
    int len = lens[b];
    float* sc = attn + (size_t)b * S_;
    feat[b * E_ + t] = 0.f;
    feat[b * E_ + 256 + t] = 0.f;
    float v[8];
    #pragma unroll
    for (int i = 0; i < 8; ++i) {
        int s = t + i * 256;
        v[i] = (s < len) ? sc[s] : -1e30f;
    }
    float m = -1e30f;
    #pragma unroll
    for (int i = 0; i < 8; ++i) m = fmaxf(m, v[i]);
    #pragma unroll
    for (int off = 32; off >= 1; off >>= 1) m = fmaxf(m, __shfl_xor(m, off));
    if ((t & 63) == 0) redm[t >> 6] = m;
    __syncthreads();
    m = fmaxf(fmaxf(redm[0], redm[1]), fmaxf(redm[2], redm[3]));
    float e[8]; float tm = 0.f;
    #pragma unroll
    for (int i = 0; i < 8; ++i) {
        int s = t + i * 256;
        e[i] = (s < len) ? __expf(v[i] - m) : 0.f;
        tm += e[i];
    }
    #pragma unroll
    for (int off = 32; off >= 1; off >>= 1) tm += __shfl_xor(tm, off);
    if ((t & 63) == 0) redt[t >> 6] = tm;
    __syncthreads();
    tm = redt[0] + redt[1] + redt[2] + redt[3];
    float sfac = 1.f / tm;
    #pragma unroll
    for (int i = 0; i < 8; ++i) {
        int s = t + i * 256;
        sc[s] = e[i] * sfac;
    }
}

// ---- attention_features[b,e] = sum_{s<len} attn[b,s]*embeds[b,s,e] ----
__global__ __launch_bounds__(512) void wsum_kernel(
    const float* __restrict__ A, const float* __restrict__ attn,
    const int* __restrict__ lens, float* __restrict__ out) {
    int b = blockIdx.y;
    int len = lens[b];
    int s0 = blockIdx.x * 128;
    if (s0 >= len) return;
    int send = s0 + 128; if (send > len) send = len;
    int t  = threadIdx.x;
    int e4 = t & 127;   // float4 column
    int sr = t >> 7;    // row group 0..3
    const float* ap = attn + (size_t)b * S_;
    f32x4 acc = {0.f, 0.f, 0.f, 0.f};
    const float* base = A + (size_t)b * S_ * E_;
    for (int s = s0 + sr; s < send; s += 4) {
        float wgt = ap[s];
        f32x4 v = *(const f32x4*)(base + (size_t)s * E_ + e4 * 4);
        acc += wgt * v;
    }
    __shared__ f32x4 red[4][128];
    red[sr][e4] = acc;
    __syncthreads();
    if (t < 128) {
        f32x4 tot = red[0][t] + red[1][t] + red[2][t] + red[3][t];
        float* o = out + (size_t)b * E_ + t * 4;
        atomicAdd(o + 0, tot[0]);
        atomicAdd(o + 1, tot[1]);
        atomicAdd(o + 2, tot[2]);
        atomicAdd(o + 3, tot[3]);
    }
}

extern "C" void kernel_launch(void* const* d_in, const int* in_sizes, int n_in,
                              void* d_out, int out_size, void* d_ws, size_t ws_size,
                              hipStream_t stream) {
    const float* embeds = (const float*)d_in[0];
    const int*   lens   = (const int*)d_in[1];
    const float* ctx    = (const float*)d_in[2];
    const float* Ww     = (const float*)d_in[3];
    const float* bw     = (const float*)d_in[4];
    const float* Wc     = (const float*)d_in[5];
    const float* bc     = (const float*)d_in[6];
    const float* wh     = (const float*)d_in[7];
    float* out  = (float*)d_out;
    float* feat = out;                 // [B, E]
    float* attn = out + B_ * E_;       // [B, S] (raw scores, then attn; 0 for s>=len)

    unsigned short* Wb = (unsigned short*)d_ws;                                  // 256 KB
    float* cb = (float*)((char*)d_ws + (size_t)H_ * E_ * sizeof(unsigned short)); // 64 KB

    prep_kernel<<<192, 256, 0, stream>>>(Ww, Wb, ctx, Wc, bc, bw, cb);
    scores_kernel<<<dim3(B_ * S_ / BM), 512, 0, stream>>>(embeds, Wb, cb, wh, lens, attn);
    softmax_kernel<<<B_, 256, 0, stream>>>(lens, attn, feat);
    wsum_kernel<<<dim3(S_ / 128, B_), 512, 0, stream>>>(embeds, attn, lens, feat);
}

// Round 8
// 406.638 us; speedup vs baseline: 1.0681x; 1.0105x over previous
//
#include <hip/hip_runtime.h>
#include <hip/hip_bf16.h>
#include <cstdint>
#include <cstddef>

#define B_  64
#define S_  2048
#define E_  512
#define C_  512
#define H_  256

using f32x4 = __attribute__((ext_vector_type(4))) float;
using s16x8 = __attribute__((ext_vector_type(8))) short;

// packed fp32x4 -> bf16x4 (RNE)
__device__ __forceinline__ uint2 f4_to_bf4(float4 v) {
    __hip_bfloat162 lo = __float22bfloat162_rn(make_float2(v.x, v.y));
    __hip_bfloat162 hi = __float22bfloat162_rn(make_float2(v.z, v.w));
    union { __hip_bfloat162 b; unsigned u; } a, c;
    a.b = lo; c.b = hi;
    return make_uint2(a.u, c.u);
}

// async global->LDS DMA, 16 B per lane; lds dest = wave-uniform base + lane*16
__device__ __forceinline__ void async16(const void* g, void* l) {
    __builtin_amdgcn_global_load_lds(
        (const __attribute__((address_space(1))) void*)g,
        (__attribute__((address_space(3))) void*)l,
        16, 0, 0);
}

// ---- merged prep: blocks 0..127 convert W_word to bf16; blocks 128..191 do
// cb[b][h] = ctx[b]@W_ctx[h]^T + b_ctx[h] + b_word[h] ----
__global__ void prep_kernel(const float* __restrict__ W, unsigned short* __restrict__ Wb,
                            const float* __restrict__ ctx, const float* __restrict__ Wc,
                            const float* __restrict__ bc, const float* __restrict__ bw,
                            float* __restrict__ cb) {
    __shared__ float row[C_];
    int blk = blockIdx.x, t = threadIdx.x;
    if (blk < 128) {
        int i = (blk * 256 + t) * 4;
        float4 v = *(const float4*)(W + i);
        *(uint2*)(Wb + i) = f4_to_bf4(v);
    } else {
        int b = blk - 128;
        row[t] = ctx[b * C_ + t];
        row[t + 256] = ctx[b * C_ + t + 256];
        __syncthreads();
        const float4* w4 = (const float4*)(Wc + (size_t)t * C_);
        const float4* x4 = (const float4*)row;
        float acc = 0.f;
        #pragma unroll 4
        for (int c = 0; c < C_ / 4; ++c) {
            float4 w = w4[c], x = x4[c];
            acc += w.x * x.x + w.y * x.y + w.z * x.z + w.w * x.w;
        }
        cb[b * H_ + t] = acc + bc[t] + bw[t];
    }
}

// ---- main: scores[b,s] = w_hidden . tanh(embeds[b,s]@W_word^T + cb[b]) ----
// Session-best structure (83 us scores / 408 us total). Seven variants
// (de-stage, fusion, full-dbuf, A-dbuf, BM=64 retile, T3 counted-wait)
// all measured neutral-to-worse; the limiter is the mixed HBM/L3 feed
// rate of the A stream, not barrier drains (R7 null proved this).
// Mixed staging: A (fp32) via register roundtrip + convert-once into padded
// LDS (single ds_read_b128 per fragment); B (bf16) via global_load_lds DMA
// into XOR-swizzled unpadded LDS (chunk p of row r = global chunk p^(r&7)).
// B DMA issued FIRST so its HBM latency hides under A's staging VALU.
#define BM 128
#define BN 256
#define BK 64
#define LDT 72   // padded LDS row stride for A (shorts)

__global__ __launch_bounds__(512) void scores_kernel(
    const float* __restrict__ A,            // [B*S, E] fp32
    const unsigned short* __restrict__ Wb,  // [H, E] bf16
    const float* __restrict__ cb,           // [B, H]
    const float* __restrict__ wh,           // [H]
    const int*   __restrict__ lens,         // [B]
    float* __restrict__ scores)             // [B*S]
{
    __shared__ __align__(16) unsigned short At[BM * LDT];   // 18.4 KB, padded
    __shared__ __align__(16) unsigned short Bt[BN * 64];    // 32 KB, DMA target (no pad)
    __shared__ float sblk[BM];
    int t = threadIdx.x;
    int m0 = blockIdx.x * BM;
    int b  = m0 >> 11;   // /S_
    int ms = m0 & (S_ - 1);
    if (ms >= lens[b]) return;   // fully-masked slab: dead work

    int w = t >> 6, lane = t & 63, quad = lane >> 4, lm = lane & 15;
    int wm = (w & 1) * 64, wn = (w >> 1) * 64;

    if (t < BM) sblk[t] = 0.f;

    f32x4 acc[4][4] = {};

    int arow = t >> 4, acol = (t & 15) * 4;  // A staging: 32 rows/sweep, 4 sweeps
    int la8 = lane >> 3, lc8 = lane & 7;     // B DMA: 8 rows/inst, 8 chunks/row

    for (int k0 = 0; k0 < E_; k0 += BK) {
        // B: 8 waves x 4 DMA insts -> 256 rows x 128 B (issued first, stays in flight)
        #pragma unroll
        for (int j = 0; j < 4; ++j) {
            int r  = (w << 5) + (j << 3) + la8;
            int cg = (lc8 ^ (r & 7)) << 3;               // swizzled global short offset
            async16(Wb + (size_t)r * E_ + k0 + cg,
                    (char*)Bt + (((w << 5) + (j << 3)) << 7));
        }
        // A: register roundtrip, convert once at staging
        #pragma unroll
        for (int i = 0; i < 4; ++i) {
            int r = arow + i * 32;
            float4 v = *(const float4*)(A + (size_t)(m0 + r) * E_ + k0 + acol);
            *(uint2*)(At + r * LDT + acol) = f4_to_bf4(v);
        }
        __syncthreads();
        #pragma unroll
        for (int ks = 0; ks < 2; ++ks) {
            s16x8 af[4], bfr[4];
            #pragma unroll
            for (int i = 0; i < 4; ++i)
                af[i] = *(const s16x8*)(At + (wm + i * 16 + lm) * LDT + ks * 32 + quad * 8);
            #pragma unroll
            for (int i = 0; i < 4; ++i) {
                int r = wn + i * 16 + lm;
                int c = (ks * 4 + quad) ^ (r & 7);
                bfr[i] = *(const s16x8*)(Bt + r * 64 + c * 8);
            }
            #pragma unroll
            for (int mi = 0; mi < 4; ++mi)
                #pragma unroll
                for (int ni = 0; ni < 4; ++ni)
                    acc[mi][ni] = __builtin_amdgcn_mfma_f32_16x16x32_bf16(
                        af[mi], bfr[ni], acc[mi][ni], 0, 0, 0);
        }
        __syncthreads();
    }

    float wv[4], cbv[4];
    #pragma unroll
    for (int ni = 0; ni < 4; ++ni) {
        int n = wn + ni * 16 + lm;
        wv[ni]  = wh[n];
        cbv[ni] = cb[b * H_ + n];
    }
    #pragma unroll
    for (int mi = 0; mi < 4; ++mi) {
        #pragma unroll
        for (int r = 0; r < 4; ++r) {
            float p = 0.f;
            #pragma unroll
            for (int ni = 0; ni < 4; ++ni) {
                float x = acc[mi][ni][r] + cbv[ni];
                x = fminf(fmaxf(x, -15.f), 15.f);
                float e = __expf(2.f * x);
                float th = 1.f - 2.f * __builtin_amdgcn_rcpf(e + 1.f);
                p += wv[ni] * th;
            }
            #pragma unroll
            for (int off = 8; off >= 1; off >>= 1)
                p += __shfl_xor(p, off);
            if (lm == 0)
                atomicAdd(&sblk[wm + mi * 16 + quad * 4 + r], p);
        }
    }
    __syncthreads();
    if (t < BM) scores[m0 + t] = sblk[t];
}

// ---- masked softmax over s<len; attn=0 for s>=len. Also zeroes feat[b,:]
// (wsum accumulates with atomics and runs after this in stream order).
__global__ void softmax_kernel(const int* __restrict__ lens, float* __restrict__ attn,
                               float* __restrict__ feat) {
    __shared__ float redm[4], redt[4];
    int b = blockIdx.x, t = threadIdx.x;
    int len = lens[b];
    float* sc = attn + (size_t)b * S_;
    feat[b * E_ + t] = 0.f;
    feat[b * E_ + 256 + t] = 0.f;
    float v[8];
    #pragma unroll
    for (int i = 0; i < 8; ++i) {
        int s = t + i * 256;
        v[i] = (s < len) ? sc[s] : -1e30f;
    }
    float m = -1e30f;
    #pragma unroll
    for (int i = 0; i < 8; ++i) m = fmaxf(m, v[i]);
    #pragma unroll
    for (int off = 32; off >= 1; off >>= 1) m = fmaxf(m, __shfl_xor(m, off));
    if ((t & 63) == 0) redm[t >> 6] = m;
    __syncthreads();
    m = fmaxf(fmaxf(redm[0], redm[1]), fmaxf(redm[2], redm[3]));
    float e[8]; float tm = 0.f;
    #pragma unroll
    for (int i = 0; i < 8; ++i) {
        int s = t + i * 256;
        e[i] = (s < len) ? __expf(v[i] - m) : 0.f;
        tm += e[i];
    }
    #pragma unroll
    for (int off = 32; off >= 1; off >>= 1) tm += __shfl_xor(tm, off);
    if ((t & 63) == 0) redt[t >> 6] = tm;
    __syncthreads();
    tm = redt[0] + redt[1] + redt[2] + redt[3];
    float sfac = 1.f / tm;
    #pragma unroll
    for (int i = 0; i < 8; ++i) {
        int s = t + i * 256;
        sc[s] = e[i] * sfac;
    }
}

// ---- attention_features[b,e] = sum_{s<len} attn[b,s]*embeds[b,s,e] ----
__global__ __launch_bounds__(512) void wsum_kernel(
    const float* __restrict__ A, const float* __restrict__ attn,
    const int* __restrict__ lens, float* __restrict__ out) {
    int b = blockIdx.y;
    int len = lens[b];
    int s0 = blockIdx.x * 128;
    if (s0 >= len) return;
    int send = s0 + 128; if (send > len) send = len;
    int t  = threadIdx.x;
    int e4 = t & 127;   // float4 column
    int sr = t >> 7;    // row group 0..3
    const float* ap = attn + (size_t)b * S_;
    f32x4 acc = {0.f, 0.f, 0.f, 0.f};
    const float* base = A + (size_t)b * S_ * E_;
    for (int s = s0 + sr; s < send; s += 4) {
        float wgt = ap[s];
        f32x4 v = *(const f32x4*)(base + (size_t)s * E_ + e4 * 4);
        acc += wgt * v;
    }
    __shared__ f32x4 red[4][128];
    red[sr][e4] = acc;
    __syncthreads();
    if (t < 128) {
        f32x4 tot = red[0][t] + red[1][t] + red[2][t] + red[3][t];
        float* o = out + (size_t)b * E_ + t * 4;
        atomicAdd(o + 0, tot[0]);
        atomicAdd(o + 1, tot[1]);
        atomicAdd(o + 2, tot[2]);
        atomicAdd(o + 3, tot[3]);
    }
}

extern "C" void kernel_launch(void* const* d_in, const int* in_sizes, int n_in,
                              void* d_out, int out_size, void* d_ws, size_t ws_size,
                              hipStream_t stream) {
    const float* embeds = (const float*)d_in[0];
    const int*   lens   = (const int*)d_in[1];
    const float* ctx    = (const float*)d_in[2];
    const float* Ww     = (const float*)d_in[3];
    const float* bw     = (const float*)d_in[4];
    const float* Wc     = (const float*)d_in[5];
    const float* bc     = (const float*)d_in[6];
    const float* wh     = (const float*)d_in[7];
    float* out  = (float*)d_out;
    float* feat = out;                 // [B, E]
    float* attn = out + B_ * E_;       // [B, S] (raw scores, then attn; 0 for s>=len)

    unsigned short* Wb = (unsigned short*)d_ws;                                  // 256 KB
    float* cb = (float*)((char*)d_ws + (size_t)H_ * E_ * sizeof(unsigned short)); // 64 KB

    prep_kernel<<<192, 256, 0, stream>>>(Ww, Wb, ctx, Wc, bc, bw, cb);
    scores_kernel<<<dim3(B_ * S_ / BM), 512, 0, stream>>>(embeds, Wb, cb, wh, lens, attn);
    softmax_kernel<<<B_, 256, 0, stream>>>(lens, attn, feat);
    wsum_kernel<<<dim3(S_ / 128, B_), 512, 0, stream>>>(embeds, attn, lens, feat);
}